// Round 13
// baseline (324.123 us; speedup 1.0000x reference)
//
#include <hip/hip_runtime.h>

#define N_NODES  50000
#define N_EDGES  600000
#define N_GRAPHS 512

#define SCAN_N   (N_NODES + 1)
#define SCAN_BPB 1024
#define SCAN_NB  ((SCAN_N + SCAN_BPB - 1) / SCAN_BPB)   // 49

#define F2BF_BLOCKS 6250   // N_NODES*128/4/256
#define ZR_BLOCKS   196    // ceil(50001/256)
#define WC_BLOCKS   224    // ceil(57344/256)

typedef __attribute__((ext_vector_type(8))) short bf16x8;
typedef __attribute__((ext_vector_type(4))) float f32x4;

// bf16 helpers (RNE pack, shift unpack)
static __device__ __forceinline__ unsigned f2bf(float f) {
    unsigned u = __float_as_uint(f);
    return (u + 0x7FFFu + ((u >> 16) & 1u)) >> 16;
}
static __device__ __forceinline__ float bflo(unsigned v) { return __uint_as_float(v << 16); }
static __device__ __forceinline__ float bfhi(unsigned v) { return __uint_as_float(v & 0xFFFF0000u); }

static __device__ __forceinline__ void addv8(float* acc, uint4 v) {
    acc[0] += bflo(v.x); acc[1] += bfhi(v.x);
    acc[2] += bflo(v.y); acc[3] += bfhi(v.y);
    acc[4] += bflo(v.z); acc[5] += bfhi(v.z);
    acc[6] += bflo(v.w); acc[7] += bfhi(v.w);
}

// ---------------- fused init: f2bf(x) + zero rowptr + weight convert -------

__global__ void init_kernel(const float* __restrict__ x, uint2* __restrict__ xb,
                            int* __restrict__ rowptr,
                            const float* __restrict__ w1r, const float* __restrict__ w1o,
                            const float* __restrict__ w2r, const float* __restrict__ w2o,
                            const float* __restrict__ w3r, const float* __restrict__ w3o,
                            unsigned short* __restrict__ wdst) {
    int b = blockIdx.x, t = threadIdx.x;
    if (b < F2BF_BLOCKS) {
        int i = b * 256 + t;  // exactly N_NODES*32 threads
        float4 v = ((const float4*)x)[i];
        uint2 o;
        o.x = f2bf(v.x) | (f2bf(v.y) << 16);
        o.y = f2bf(v.z) | (f2bf(v.w) << 16);
        xb[i] = o;
    } else if (b < F2BF_BLOCKS + ZR_BLOCKS) {
        int i = (b - F2BF_BLOCKS) * 256 + t;
        if (i < SCAN_N) rowptr[i] = 0;
    } else {
        int i = (b - F2BF_BLOCKS - ZR_BLOCKS) * 256 + t;
        const float* src; int off;
        if      (i < 16384) { src = w1r; off = 0; }
        else if (i < 32768) { src = w1o; off = 16384; }
        else if (i < 40960) { src = w2r; off = 32768; }
        else if (i < 49152) { src = w2o; off = 40960; }
        else if (i < 53248) { src = w3r; off = 49152; }
        else if (i < 57344) { src = w3o; off = 53248; }
        else return;
        wdst[i] = (unsigned short)f2bf(src[i - off]);
    }
}

// ---------------- CSR build ----------------

__global__ void hist_kernel(const int* __restrict__ edge, int* __restrict__ rowptr) {
    int e = blockIdx.x * blockDim.x + threadIdx.x;
    if (e < N_EDGES) atomicAdd(&rowptr[edge[N_EDGES + e] + 1], 1);
}

__global__ void scan_reduce_kernel(const int* __restrict__ data, int* __restrict__ bsum) {
    __shared__ int red[256];
    int b = blockIdx.x, t = threadIdx.x;
    int base = b * SCAN_BPB + t * 4;
    int s = 0;
#pragma unroll
    for (int j = 0; j < 4; ++j) {
        int idx = base + j;
        if (idx < SCAN_N) s += data[idx];
    }
    red[t] = s;
    __syncthreads();
    for (int off = 128; off > 0; off >>= 1) {
        if (t < off) red[t] += red[t + off];
        __syncthreads();
    }
    if (t == 0) bsum[b] = red[0];
}

// scan_apply with inline block-offset computation (scan_sums folded in) + cursor init
__global__ void scan_apply_kernel(int* __restrict__ data, const int* __restrict__ bsum,
                                  int* __restrict__ cursor) {
    __shared__ int th[256];
    __shared__ int boff;
    int b = blockIdx.x, t = threadIdx.x;
    if (t == 0) {
        int run = 0;
        for (int i = 0; i < b; ++i) run += bsum[i];
        boff = run;
    }
    int base = b * SCAN_BPB + t * 4;
    int v[4];
    int s = 0;
#pragma unroll
    for (int j = 0; j < 4; ++j) {
        int idx = base + j;
        v[j] = (idx < SCAN_N) ? data[idx] : 0;
        s += v[j];
    }
    th[t] = s;
    __syncthreads();
    for (int off = 1; off < 256; off <<= 1) {
        int x = (t >= off) ? th[t - off] : 0;
        __syncthreads();
        th[t] += x;
        __syncthreads();
    }
    int run = boff + th[t] - s;
#pragma unroll
    for (int j = 0; j < 4; ++j) {
        int idx = base + j;
        run += v[j];
        if (idx < SCAN_N) {
            data[idx] = run;
            if (idx < N_NODES) cursor[idx] = run;
        }
    }
}

__global__ void scatter_kernel(const int* __restrict__ edge, int* __restrict__ cursor,
                               int* __restrict__ csr) {
    int e = blockIdx.x * blockDim.x + threadIdx.x;
    if (e < N_EDGES) {
        int d = edge[N_EDGES + e];
        int p = atomicAdd(&cursor[d], 1);
        csr[p] = edge[e];
    }
}

// ---------------- bf16 aggregation, uint4 lanes (16B), 8-deep ILP ----------
// Row = LPN*8 bf16 features; lane owns 8 features.
// MODE 0: OUT = bf16(aggr)                (layer-1 pre-GEMM)
// MODE 1: OUT = bf16(relu(aggr + ROOT))   (layer-2 h)
// MODE 2: OUT = f32(aggr + ROOT)          (layer-3 h, feeds pool)
template <int LPN, int MODE>
__global__ void aggregate_u4(const unsigned short* __restrict__ Xb,
                             const int* __restrict__ rowptr,
                             const int* __restrict__ csr,
                             const unsigned short* __restrict__ ROOT,
                             void* __restrict__ OUT) {
    constexpr int NPB = 256 / LPN;
    int grp = threadIdx.x / LPN, lane = threadIdx.x % LPN;
    int i = blockIdx.x * NPB + grp;
    if (i >= N_NODES) return;
    const uint4* __restrict__ X4 = (const uint4*)Xb;
    int s = rowptr[i], e = rowptr[i + 1];
    float a[8] = {0.f}, b[8] = {0.f};
    int p = s;
    // 8-deep: 8 independent 16B loads in flight before first use
    for (; p + 8 <= e; p += 8) {
        uint4 v0 = X4[(size_t)csr[p + 0] * LPN + lane];
        uint4 v1 = X4[(size_t)csr[p + 1] * LPN + lane];
        uint4 v2 = X4[(size_t)csr[p + 2] * LPN + lane];
        uint4 v3 = X4[(size_t)csr[p + 3] * LPN + lane];
        uint4 v4 = X4[(size_t)csr[p + 4] * LPN + lane];
        uint4 v5 = X4[(size_t)csr[p + 5] * LPN + lane];
        uint4 v6 = X4[(size_t)csr[p + 6] * LPN + lane];
        uint4 v7 = X4[(size_t)csr[p + 7] * LPN + lane];
        addv8(a, v0); addv8(b, v1); addv8(a, v2); addv8(b, v3);
        addv8(a, v4); addv8(b, v5); addv8(a, v6); addv8(b, v7);
    }
    if (p + 4 <= e) {
        uint4 v0 = X4[(size_t)csr[p + 0] * LPN + lane];
        uint4 v1 = X4[(size_t)csr[p + 1] * LPN + lane];
        uint4 v2 = X4[(size_t)csr[p + 2] * LPN + lane];
        uint4 v3 = X4[(size_t)csr[p + 3] * LPN + lane];
        addv8(a, v0); addv8(b, v1); addv8(a, v2); addv8(b, v3);
        p += 4;
    }
    if (p + 2 <= e) {
        uint4 v0 = X4[(size_t)csr[p] * LPN + lane];
        uint4 v1 = X4[(size_t)csr[p + 1] * LPN + lane];
        addv8(a, v0); addv8(b, v1);
        p += 2;
    }
    if (p < e) {
        uint4 v = X4[(size_t)csr[p] * LPN + lane];
        addv8(a, v);
    }
    float f[8];
#pragma unroll
    for (int k = 0; k < 8; ++k) f[k] = a[k] + b[k];
    if constexpr (MODE != 0) {
        uint4 r = ((const uint4*)ROOT)[(size_t)i * LPN + lane];
        f[0] += bflo(r.x); f[1] += bfhi(r.x);
        f[2] += bflo(r.y); f[3] += bfhi(r.y);
        f[4] += bflo(r.z); f[5] += bfhi(r.z);
        f[6] += bflo(r.w); f[7] += bfhi(r.w);
    }
    if constexpr (MODE == 1) {
#pragma unroll
        for (int k = 0; k < 8; ++k) f[k] = fmaxf(f[k], 0.f);
    }
    if constexpr (MODE == 2) {
        float* row = (float*)OUT + (size_t)i * (LPN * 8) + lane * 8;
        *(float4*)row       = make_float4(f[0], f[1], f[2], f[3]);
        *(float4*)(row + 4) = make_float4(f[4], f[5], f[6], f[7]);
    } else {
        uint4 o;
        o.x = f2bf(f[0]) | (f2bf(f[1]) << 16);
        o.y = f2bf(f[2]) | (f2bf(f[3]) << 16);
        o.z = f2bf(f[4]) | (f2bf(f[5]) << 16);
        o.w = f2bf(f[6]) | (f2bf(f[7]) << 16);
        ((uint4*)OUT)[(size_t)i * LPN + lane] = o;
    }
}

// ---------------- MFMA GEMM (layer 1, concat-K, single output) -------------

template <int KS1, int KS2, int NT>
__launch_bounds__(256, 2)
__global__ void gemm_mfma(const unsigned short* __restrict__ A1,
                          const unsigned short* __restrict__ W1,
                          const unsigned short* __restrict__ A2,
                          const unsigned short* __restrict__ W2,
                          const float* __restrict__ bias,
                          unsigned short* __restrict__ OUT, int ldo) {
    constexpr int K1 = KS1 * 32, K2 = KS2 * 32;
    const int l  = threadIdx.x & 63;
    const int wv = threadIdx.x >> 6;
    const int lm = l & 15, lk = l >> 4;
    const int colbase = wv * (NT * 16);

    bf16x8 wf[NT][KS1 + KS2];
#pragma unroll
    for (int t = 0; t < NT; ++t) {
        int wrow = colbase + t * 16 + lm;
#pragma unroll
        for (int ks = 0; ks < KS1; ++ks)
            wf[t][ks] = *(const bf16x8*)(W1 + (size_t)wrow * K1 + ks * 32 + lk * 8);
#pragma unroll
        for (int ks = 0; ks < KS2; ++ks)
            wf[t][KS1 + ks] = *(const bf16x8*)(W2 + (size_t)wrow * K2 + ks * 32 + lk * 8);
    }

    int rt0 = blockIdx.x * 4;
    for (int r = 0; r < 4; ++r) {
        int rt = rt0 + r;
        if (rt >= N_NODES / 16) break;
        f32x4 acc[NT];
#pragma unroll
        for (int t = 0; t < NT; ++t) acc[t] = (f32x4){0.f, 0.f, 0.f, 0.f};

        const unsigned short* a1row = A1 + (size_t)(rt * 16 + lm) * K1 + lk * 8;
#pragma unroll
        for (int ks = 0; ks < KS1; ++ks) {
            bf16x8 a = *(const bf16x8*)(a1row + ks * 32);
#pragma unroll
            for (int t = 0; t < NT; ++t)
                acc[t] = __builtin_amdgcn_mfma_f32_16x16x32_bf16(a, wf[t][ks], acc[t], 0, 0, 0);
        }
        const unsigned short* a2row = A2 + (size_t)(rt * 16 + lm) * K2 + lk * 8;
#pragma unroll
        for (int ks = 0; ks < KS2; ++ks) {
            bf16x8 a = *(const bf16x8*)(a2row + ks * 32);
#pragma unroll
            for (int t = 0; t < NT; ++t)
                acc[t] = __builtin_amdgcn_mfma_f32_16x16x32_bf16(a, wf[t][KS1 + ks], acc[t], 0, 0, 0);
        }
#pragma unroll
        for (int t = 0; t < NT; ++t) {
            int n = colbase + t * 16 + lm;
            float bv = bias[n];
#pragma unroll
            for (int j = 0; j < 4; ++j) {
                int m = rt * 16 + lk * 4 + j;
                float v = fmaxf(acc[t][j] + bv, 0.f);
                OUT[(size_t)m * ldo + n] = (unsigned short)f2bf(v);
            }
        }
    }
}

// ---------------- MFMA dual GEMM (layers 2/3) ------------------------------
// W = [128][K] = Wrel rows 0..63 ‖ Wroot rows 64..127 (contiguous in wbf).
template <int KS>
__launch_bounds__(256, 2)
__global__ void gemm_dual(const unsigned short* __restrict__ A,
                          const unsigned short* __restrict__ W,
                          const float* __restrict__ bias,
                          unsigned short* __restrict__ OUTY,
                          unsigned short* __restrict__ OUTR) {
    constexpr int K = KS * 32, NT = 2;
    const int l  = threadIdx.x & 63;
    const int wv = threadIdx.x >> 6;
    const int lm = l & 15, lk = l >> 4;
    const int colbase = wv * (NT * 16);

    bf16x8 wf[NT][KS];
#pragma unroll
    for (int t = 0; t < NT; ++t) {
        int wrow = colbase + t * 16 + lm;
#pragma unroll
        for (int ks = 0; ks < KS; ++ks)
            wf[t][ks] = *(const bf16x8*)(W + (size_t)wrow * K + ks * 32 + lk * 8);
    }

    int rt0 = blockIdx.x * 4;
    for (int r = 0; r < 4; ++r) {
        int rt = rt0 + r;
        if (rt >= N_NODES / 16) break;
        f32x4 acc[NT];
#pragma unroll
        for (int t = 0; t < NT; ++t) acc[t] = (f32x4){0.f, 0.f, 0.f, 0.f};

        const unsigned short* arow = A + (size_t)(rt * 16 + lm) * K + lk * 8;
#pragma unroll
        for (int ks = 0; ks < KS; ++ks) {
            bf16x8 a = *(const bf16x8*)(arow + ks * 32);
#pragma unroll
            for (int t = 0; t < NT; ++t)
                acc[t] = __builtin_amdgcn_mfma_f32_16x16x32_bf16(a, wf[t][ks], acc[t], 0, 0, 0);
        }
#pragma unroll
        for (int t = 0; t < NT; ++t) {
            int n = colbase + t * 16 + lm;
#pragma unroll
            for (int j = 0; j < 4; ++j) {
                int m = rt * 16 + lk * 4 + j;
                float v = acc[t][j];
                if (n < 64) {
                    OUTY[(size_t)m * 64 + n] = (unsigned short)f2bf(v);
                } else {
                    v += bias[n - 64];
                    OUTR[(size_t)m * 64 + (n - 64)] = (unsigned short)f2bf(v);
                }
            }
        }
    }
}

// ---------------- per-graph pooling (sorted batch, binary search) ----------

__global__ void pool_graph(const float* __restrict__ H, const int* __restrict__ batch,
                           float* __restrict__ G) {
    int g = blockIdx.x;   // 512 blocks
    int t = threadIdx.x;  // 64 threads
    // lower_bound(batch, g) and lower_bound(batch, g+1); all threads same path
    int lo = 0, hi = N_NODES;
    while (lo < hi) { int mid = (lo + hi) >> 1; if (batch[mid] < g) lo = mid + 1; else hi = mid; }
    int start = lo;
    hi = N_NODES;
    while (lo < hi) { int mid = (lo + hi) >> 1; if (batch[mid] < g + 1) lo = mid + 1; else hi = mid; }
    int end = lo;
    float acc = 0.f;
    for (int i = start; i < end; ++i) acc += H[(size_t)i * 64 + t];
    G[(size_t)g * 64 + t] = acc;
}

// ---------------- MLP head + log_softmax ----------------

__global__ void mlp_head(const float* __restrict__ G, const float* __restrict__ fc1w,
                         const float* __restrict__ fc1b, const float* __restrict__ fc2w,
                         const float* __restrict__ fc2b, float* __restrict__ out) {
    int g = blockIdx.x;
    int t = threadIdx.x;  // 64
    __shared__ float gr[64], tt[64], sc[32], red[2];
    gr[t] = G[(size_t)g * 64 + t];
    __syncthreads();
    float acc = fc1b[t];
#pragma unroll
    for (int k = 0; k < 64; ++k) acc += gr[k] * fc1w[t * 64 + k];
    tt[t] = fmaxf(acc, 0.f);
    __syncthreads();
    if (t < 32) {
        float s = fc2b[t];
#pragma unroll
        for (int k = 0; k < 64; ++k) s += tt[k] * fc2w[t * 64 + k];
        sc[t] = s;
    }
    __syncthreads();
    if (t == 0) {
        float mx = sc[0];
        for (int c = 1; c < 32; ++c) mx = fmaxf(mx, sc[c]);
        float sum = 0.f;
        for (int c = 0; c < 32; ++c) sum += expf(sc[c] - mx);
        red[0] = mx; red[1] = logf(sum);
    }
    __syncthreads();
    if (t < 32) out[(size_t)g * 32 + t] = sc[t] - red[0] - red[1];
}

// ---------------- launch ----------------

extern "C" void kernel_launch(void* const* d_in, const int* in_sizes, int n_in,
                              void* d_out, int out_size, void* d_ws, size_t ws_size,
                              hipStream_t stream) {
    const float* x       = (const float*)d_in[0];
    const int*   edge    = (const int*)d_in[1];   // [2][E]: row0=src, row1=dst
    const int*   batch   = (const int*)d_in[2];
    const float* w1_rel  = (const float*)d_in[3];
    const float* b1      = (const float*)d_in[4];
    const float* w1_root = (const float*)d_in[5];
    const float* w2_rel  = (const float*)d_in[6];
    const float* b2      = (const float*)d_in[7];
    const float* w2_root = (const float*)d_in[8];
    const float* w3_rel  = (const float*)d_in[9];
    const float* b3      = (const float*)d_in[10];
    const float* w3_root = (const float*)d_in[11];
    const float* fc1w    = (const float*)d_in[12];
    const float* fc1b    = (const float*)d_in[13];
    const float* fc2w    = (const float*)d_in[14];
    const float* fc2b    = (const float*)d_in[15];
    float* out = (float*)d_out;

    char* p = (char*)d_ws;
    size_t used = 0;
    auto alloc = [&](size_t bytes) {
        char* r = p + used;
        used += (bytes + 255) & ~(size_t)255;
        return r;
    };
    int*            rowptr = (int*)alloc((N_NODES + 1) * sizeof(int));
    int*            cursor = (int*)alloc(N_NODES * sizeof(int));
    int*            csr    = (int*)alloc(N_EDGES * sizeof(int));
    int*            bsum   = (int*)alloc(SCAN_NB * sizeof(int));
    unsigned short* wbf    = (unsigned short*)alloc(57344 * sizeof(unsigned short));
    unsigned short* bufX   = (unsigned short*)alloc((size_t)N_NODES * 128 * 2);  // region X
    unsigned short* bufA   = (unsigned short*)alloc((size_t)N_NODES * 128 * 2);  // region A
    unsigned short* bufH   = (unsigned short*)alloc((size_t)N_NODES * 128 * 2);  // region H
    float*          G      = (float*)alloc((size_t)N_GRAPHS * 64 * sizeof(float));

    if (used > ws_size) return;  // clean bail instead of wild writes

    // bf16 weight views (r/o pairs contiguous -> dual-GEMM concat W)
    unsigned short* w1r_bf = wbf;          // [128][128]
    unsigned short* w1o_bf = wbf + 16384;  // [128][128]
    unsigned short* w2cat  = wbf + 32768;  // [128][128]: w2_rel ‖ w2_root
    unsigned short* w3cat  = wbf + 49152;  // [128][64] : w3_rel ‖ w3_root

    // Region aliasing timeline (tenant dead before reuse):
    unsigned short* XB    = bufX;                          // [N,128] bf16
    unsigned short* AGG1b = bufA;                          // [N,128] bf16
    unsigned short* H1b   = bufH;                          // [N,128] bf16
    unsigned short* Y2B   = bufX;                          // [N,64] bf16 (XB dead)
    unsigned short* ROOT2 = bufX + (size_t)N_NODES * 64;   // [N,64] bf16
    unsigned short* H2b   = bufA;                          // [N,64] bf16 (AGG1b dead)
    unsigned short* Y3B   = bufX;                          // [N,64] bf16 (Y2B dead)
    unsigned short* ROOT3 = bufX + (size_t)N_NODES * 64;   // [N,64] bf16 (ROOT2 dead)
    float*          H3    = (float*)bufH;                  // [N,64] f32 (H1b dead)

    // 1. fused init (f2bf(x), rowptr zero, weight convert)
    init_kernel<<<F2BF_BLOCKS + ZR_BLOCKS + WC_BLOCKS, 256, 0, stream>>>(
        x, (uint2*)XB, rowptr, w1_rel, w1_root, w2_rel, w2_root, w3_rel, w3_root, wbf);

    // 2-5. CSR build
    hist_kernel<<<(N_EDGES + 255) / 256, 256, 0, stream>>>(edge, rowptr);
    scan_reduce_kernel<<<SCAN_NB, 256, 0, stream>>>(rowptr, bsum);
    scan_apply_kernel<<<SCAN_NB, 256, 0, stream>>>(rowptr, bsum, cursor);
    scatter_kernel<<<(N_EDGES + 255) / 256, 256, 0, stream>>>(edge, cursor, csr);

    int gblk = (N_NODES / 16 + 3) / 4;  // 782 blocks of 4 row-tiles

    // 6-7. Layer 1: aggr1 = segsum(x); h1 = relu(aggr1@W1r + x@W1o + b1)
    aggregate_u4<16, 0><<<(N_NODES + 15) / 16, 256, 0, stream>>>(XB, rowptr, csr, nullptr, AGG1b);
    gemm_mfma<4, 4, 2><<<gblk, 256, 0, stream>>>(AGG1b, w1r_bf, XB, w1o_bf, b1, H1b, 128);

    // 8-9. Layer 2: {y2, root2} = h1@[W2r‖W2o]; h2 = relu(segsum(y2)+root2)
    gemm_dual<4><<<gblk, 256, 0, stream>>>(H1b, w2cat, b2, Y2B, ROOT2);
    aggregate_u4<8, 1><<<(N_NODES + 31) / 32, 256, 0, stream>>>(Y2B, rowptr, csr, ROOT2, H2b);

    // 10-11. Layer 3: {y3, root3} = h2@[W3r‖W3o]; h3 = segsum(y3)+root3 (f32)
    gemm_dual<2><<<gblk, 256, 0, stream>>>(H2b, w3cat, b3, Y3B, ROOT3);
    aggregate_u4<8, 2><<<(N_NODES + 31) / 32, 256, 0, stream>>>(Y3B, rowptr, csr, ROOT3, H3);

    // 12-13. Pool (atomic-free, per-graph) + head
    pool_graph<<<N_GRAPHS, 64, 0, stream>>>(H3, batch, G);
    mlp_head<<<N_GRAPHS, 64, 0, stream>>>(G, fc1w, fc1b, fc2w, fc2b, out);
}

// Round 14
// 303.189 us; speedup vs baseline: 1.0690x; 1.0690x over previous
//
#include <hip/hip_runtime.h>

#define N_NODES  50000
#define N_EDGES  600000
#define N_GRAPHS 512

#define SCAN_N   (N_NODES + 1)
#define SCAN_BPB 1024
#define SCAN_NB  ((SCAN_N + SCAN_BPB - 1) / SCAN_BPB)   // 49

#define F2BF_BLOCKS 6250   // N_NODES*128/4/256
#define ZR_BLOCKS   196    // ceil(50001/256)
#define WC_BLOCKS   224    // ceil(57344/256)
#define ZG_BLOCKS   128    // 512*64/256

typedef __attribute__((ext_vector_type(8))) short bf16x8;
typedef __attribute__((ext_vector_type(4))) float f32x4;

// bf16 helpers (RNE pack, shift unpack)
static __device__ __forceinline__ unsigned f2bf(float f) {
    unsigned u = __float_as_uint(f);
    return (u + 0x7FFFu + ((u >> 16) & 1u)) >> 16;
}
static __device__ __forceinline__ float bflo(unsigned v) { return __uint_as_float(v << 16); }
static __device__ __forceinline__ float bfhi(unsigned v) { return __uint_as_float(v & 0xFFFF0000u); }

static __device__ __forceinline__ void addv8(float* acc, uint4 v) {
    acc[0] += bflo(v.x); acc[1] += bfhi(v.x);
    acc[2] += bflo(v.y); acc[3] += bfhi(v.y);
    acc[4] += bflo(v.z); acc[5] += bfhi(v.z);
    acc[6] += bflo(v.w); acc[7] += bfhi(v.w);
}
static __device__ __forceinline__ uint4 packv8(const float* f) {
    uint4 o;
    o.x = f2bf(f[0]) | (f2bf(f[1]) << 16);
    o.y = f2bf(f[2]) | (f2bf(f[3]) << 16);
    o.z = f2bf(f[4]) | (f2bf(f[5]) << 16);
    o.w = f2bf(f[6]) | (f2bf(f[7]) << 16);
    return o;
}

// ---------------- fused init: f2bf(x) + zero rowptr + weight convert + zero G

__global__ void init_kernel(const float* __restrict__ x, uint2* __restrict__ xb,
                            int* __restrict__ rowptr,
                            const float* __restrict__ w1r, const float* __restrict__ w1o,
                            const float* __restrict__ w2r, const float* __restrict__ w2o,
                            const float* __restrict__ w3r, const float* __restrict__ w3o,
                            unsigned short* __restrict__ wdst, float* __restrict__ G) {
    int b = blockIdx.x, t = threadIdx.x;
    if (b < F2BF_BLOCKS) {
        int i = b * 256 + t;  // exactly N_NODES*32 threads
        float4 v = ((const float4*)x)[i];
        uint2 o;
        o.x = f2bf(v.x) | (f2bf(v.y) << 16);
        o.y = f2bf(v.z) | (f2bf(v.w) << 16);
        xb[i] = o;
    } else if (b < F2BF_BLOCKS + ZR_BLOCKS) {
        int i = (b - F2BF_BLOCKS) * 256 + t;
        if (i < SCAN_N) rowptr[i] = 0;
    } else if (b < F2BF_BLOCKS + ZR_BLOCKS + WC_BLOCKS) {
        int i = (b - F2BF_BLOCKS - ZR_BLOCKS) * 256 + t;
        const float* src; int off;
        if      (i < 16384) { src = w1r; off = 0; }
        else if (i < 32768) { src = w1o; off = 16384; }
        else if (i < 40960) { src = w2r; off = 32768; }
        else if (i < 49152) { src = w2o; off = 40960; }
        else if (i < 53248) { src = w3r; off = 49152; }
        else if (i < 57344) { src = w3o; off = 53248; }
        else return;
        wdst[i] = (unsigned short)f2bf(src[i - off]);
    } else {
        int i = (b - F2BF_BLOCKS - ZR_BLOCKS - WC_BLOCKS) * 256 + t;
        G[i] = 0.f;  // exactly 32768
    }
}

// ---------------- CSR build ----------------

__global__ void hist_kernel(const int* __restrict__ edge, int* __restrict__ rowptr) {
    int e = blockIdx.x * blockDim.x + threadIdx.x;
    if (e < N_EDGES) atomicAdd(&rowptr[edge[N_EDGES + e] + 1], 1);
}

__global__ void scan_reduce_kernel(const int* __restrict__ data, int* __restrict__ bsum) {
    __shared__ int red[256];
    int b = blockIdx.x, t = threadIdx.x;
    int base = b * SCAN_BPB + t * 4;
    int s = 0;
#pragma unroll
    for (int j = 0; j < 4; ++j) {
        int idx = base + j;
        if (idx < SCAN_N) s += data[idx];
    }
    red[t] = s;
    __syncthreads();
    for (int off = 128; off > 0; off >>= 1) {
        if (t < off) red[t] += red[t + off];
        __syncthreads();
    }
    if (t == 0) bsum[b] = red[0];
}

__global__ void scan_apply_kernel(int* __restrict__ data, const int* __restrict__ bsum,
                                  int* __restrict__ cursor) {
    __shared__ int th[256];
    __shared__ int boff;
    int b = blockIdx.x, t = threadIdx.x;
    if (t == 0) {
        int run = 0;
        for (int i = 0; i < b; ++i) run += bsum[i];
        boff = run;
    }
    int base = b * SCAN_BPB + t * 4;
    int v[4];
    int s = 0;
#pragma unroll
    for (int j = 0; j < 4; ++j) {
        int idx = base + j;
        v[j] = (idx < SCAN_N) ? data[idx] : 0;
        s += v[j];
    }
    th[t] = s;
    __syncthreads();
    for (int off = 1; off < 256; off <<= 1) {
        int x = (t >= off) ? th[t - off] : 0;
        __syncthreads();
        th[t] += x;
        __syncthreads();
    }
    int run = boff + th[t] - s;
#pragma unroll
    for (int j = 0; j < 4; ++j) {
        int idx = base + j;
        run += v[j];
        if (idx < SCAN_N) {
            data[idx] = run;
            if (idx < N_NODES) cursor[idx] = run;
        }
    }
}

__global__ void scatter_kernel(const int* __restrict__ edge, int* __restrict__ cursor,
                               int* __restrict__ csr) {
    int e = blockIdx.x * blockDim.x + threadIdx.x;
    if (e < N_EDGES) {
        int d = edge[N_EDGES + e];
        int p = atomicAdd(&cursor[d], 1);
        csr[p] = edge[e];
    }
}

// ---------------- standalone bf16 aggregation (layer 3: aggr+ROOT, bf16 out)

template <int LPN>
__global__ void aggregate_root(const unsigned short* __restrict__ Xb,
                               const int* __restrict__ rowptr,
                               const int* __restrict__ csr,
                               const unsigned short* __restrict__ ROOT,
                               unsigned short* __restrict__ OUT) {
    constexpr int NPB = 256 / LPN;
    int grp = threadIdx.x / LPN, lane = threadIdx.x % LPN;
    int i = blockIdx.x * NPB + grp;
    if (i >= N_NODES) return;
    const uint4* __restrict__ X4 = (const uint4*)Xb;
    int s = rowptr[i], e = rowptr[i + 1];
    float a[8] = {0.f}, b[8] = {0.f};
    int p = s;
    for (; p + 4 <= e; p += 4) {
        uint4 v0 = X4[(size_t)csr[p + 0] * LPN + lane];
        uint4 v1 = X4[(size_t)csr[p + 1] * LPN + lane];
        uint4 v2 = X4[(size_t)csr[p + 2] * LPN + lane];
        uint4 v3 = X4[(size_t)csr[p + 3] * LPN + lane];
        addv8(a, v0); addv8(b, v1); addv8(a, v2); addv8(b, v3);
    }
    if (p + 2 <= e) {
        uint4 v0 = X4[(size_t)csr[p] * LPN + lane];
        uint4 v1 = X4[(size_t)csr[p + 1] * LPN + lane];
        addv8(a, v0); addv8(b, v1);
        p += 2;
    }
    if (p < e) {
        uint4 v = X4[(size_t)csr[p] * LPN + lane];
        addv8(a, v);
    }
    float f[8];
#pragma unroll
    for (int k = 0; k < 8; ++k) f[k] = a[k] + b[k];
    uint4 r = ((const uint4*)ROOT)[(size_t)i * LPN + lane];
    f[0] += bflo(r.x); f[1] += bfhi(r.x);
    f[2] += bflo(r.y); f[3] += bfhi(r.y);
    f[4] += bflo(r.z); f[5] += bfhi(r.z);
    f[6] += bflo(r.w); f[7] += bfhi(r.w);
    ((uint4*)OUT)[(size_t)i * LPN + lane] = packv8(f);
}

// ---------------- fused layer 1: gather aggr -> LDS, concat-K MFMA ---------
// h1 = relu(segsum(XB)@W1r^T + XB@W1o^T + b1), all bf16, K=128+128.
// LDS aggr[64][16 chunks of 16B], swizzled chunk' = chunk ^ (row&7):
// writes (row fixed, 16 lanes) and reads (quarter-wave: 16 rows, chunk fixed)
// are both 2-way bank-aliased = free.
__launch_bounds__(256, 2)
__global__ void fused_l1(const unsigned short* __restrict__ XB,
                         const int* __restrict__ rowptr, const int* __restrict__ csr,
                         const unsigned short* __restrict__ W1,   // w1r [128][128]
                         const unsigned short* __restrict__ W2,   // w1o [128][128]
                         const float* __restrict__ bias,
                         unsigned short* __restrict__ OUT) {
    __shared__ unsigned short aggr[64 * 128];
    const int tid = threadIdx.x;
    const int i0 = blockIdx.x * 64;

    // Phase A: gather (16 groups x 16 lanes; 4 rows/group)
    {
        const uint4* __restrict__ X4 = (const uint4*)XB;
        int grp = tid >> 4, lane = tid & 15;
        for (int j = 0; j < 4; ++j) {
            int row = grp * 4 + j;
            int i = i0 + row;
            if (i >= N_NODES) break;
            int s = rowptr[i], e = rowptr[i + 1];
            float a[8] = {0.f}, b[8] = {0.f};
            int p = s;
            for (; p + 4 <= e; p += 4) {
                uint4 v0 = X4[(size_t)csr[p + 0] * 16 + lane];
                uint4 v1 = X4[(size_t)csr[p + 1] * 16 + lane];
                uint4 v2 = X4[(size_t)csr[p + 2] * 16 + lane];
                uint4 v3 = X4[(size_t)csr[p + 3] * 16 + lane];
                addv8(a, v0); addv8(b, v1); addv8(a, v2); addv8(b, v3);
            }
            if (p + 2 <= e) {
                uint4 v0 = X4[(size_t)csr[p] * 16 + lane];
                uint4 v1 = X4[(size_t)csr[p + 1] * 16 + lane];
                addv8(a, v0); addv8(b, v1);
                p += 2;
            }
            if (p < e) { uint4 v = X4[(size_t)csr[p] * 16 + lane]; addv8(a, v); }
            float f[8];
#pragma unroll
            for (int k = 0; k < 8; ++k) f[k] = a[k] + b[k];
            *(uint4*)&aggr[(row * 16 + (lane ^ (row & 7))) * 8] = packv8(f);
        }
    }
    // Phase B setup (global-only, no LDS dependency)
    const int l = tid & 63, wv = tid >> 6;
    const int lm = l & 15, lk = l >> 4;
    const int colbase = wv * 32;
    bf16x8 wf[2][8];
#pragma unroll
    for (int t = 0; t < 2; ++t) {
        int wrow = colbase + t * 16 + lm;
#pragma unroll
        for (int ks = 0; ks < 4; ++ks)
            wf[t][ks] = *(const bf16x8*)(W1 + (size_t)wrow * 128 + ks * 32 + lk * 8);
#pragma unroll
        for (int ks = 0; ks < 4; ++ks)
            wf[t][4 + ks] = *(const bf16x8*)(W2 + (size_t)wrow * 128 + ks * 32 + lk * 8);
    }
    __syncthreads();
    // Phase B: MFMA over 4 row-tiles
    for (int r = 0; r < 4; ++r) {
        int rt = blockIdx.x * 4 + r;
        if (rt >= N_NODES / 16) break;
        f32x4 acc0 = (f32x4){0.f, 0.f, 0.f, 0.f};
        f32x4 acc1 = (f32x4){0.f, 0.f, 0.f, 0.f};
        int ldsrow = r * 16 + lm;
#pragma unroll
        for (int ks = 0; ks < 4; ++ks) {
            int c = ks * 4 + lk;
            bf16x8 a = *(const bf16x8*)&aggr[(ldsrow * 16 + (c ^ (ldsrow & 7))) * 8];
            acc0 = __builtin_amdgcn_mfma_f32_16x16x32_bf16(a, wf[0][ks], acc0, 0, 0, 0);
            acc1 = __builtin_amdgcn_mfma_f32_16x16x32_bf16(a, wf[1][ks], acc1, 0, 0, 0);
        }
        const unsigned short* a2row = XB + (size_t)(rt * 16 + lm) * 128 + lk * 8;
#pragma unroll
        for (int ks = 0; ks < 4; ++ks) {
            bf16x8 a = *(const bf16x8*)(a2row + ks * 32);
            acc0 = __builtin_amdgcn_mfma_f32_16x16x32_bf16(a, wf[0][4 + ks], acc0, 0, 0, 0);
            acc1 = __builtin_amdgcn_mfma_f32_16x16x32_bf16(a, wf[1][4 + ks], acc1, 0, 0, 0);
        }
#pragma unroll
        for (int t = 0; t < 2; ++t) {
            int n = colbase + t * 16 + lm;
            float bv = bias[n];
            const f32x4& acc = t ? acc1 : acc0;
#pragma unroll
            for (int jj = 0; jj < 4; ++jj) {
                int m = rt * 16 + lk * 4 + jj;
                float v = fmaxf(acc[jj] + bv, 0.f);
                OUT[(size_t)m * 128 + n] = (unsigned short)f2bf(v);
            }
        }
    }
}

// ---------------- MFMA dual GEMM (layer 2) ---------------------------------
// W = [128][K]: Wrel rows 0..63 || Wroot rows 64..127.
template <int KS>
__launch_bounds__(256, 2)
__global__ void gemm_dual(const unsigned short* __restrict__ A,
                          const unsigned short* __restrict__ W,
                          const float* __restrict__ bias,
                          unsigned short* __restrict__ OUTY,
                          unsigned short* __restrict__ OUTR) {
    constexpr int K = KS * 32, NT = 2;
    const int l  = threadIdx.x & 63;
    const int wv = threadIdx.x >> 6;
    const int lm = l & 15, lk = l >> 4;
    const int colbase = wv * (NT * 16);

    bf16x8 wf[NT][KS];
#pragma unroll
    for (int t = 0; t < NT; ++t) {
        int wrow = colbase + t * 16 + lm;
#pragma unroll
        for (int ks = 0; ks < KS; ++ks)
            wf[t][ks] = *(const bf16x8*)(W + (size_t)wrow * K + ks * 32 + lk * 8);
    }

    int rt0 = blockIdx.x * 4;
    for (int r = 0; r < 4; ++r) {
        int rt = rt0 + r;
        if (rt >= N_NODES / 16) break;
        f32x4 acc[NT];
#pragma unroll
        for (int t = 0; t < NT; ++t) acc[t] = (f32x4){0.f, 0.f, 0.f, 0.f};

        const unsigned short* arow = A + (size_t)(rt * 16 + lm) * K + lk * 8;
#pragma unroll
        for (int ks = 0; ks < KS; ++ks) {
            bf16x8 a = *(const bf16x8*)(arow + ks * 32);
#pragma unroll
            for (int t = 0; t < NT; ++t)
                acc[t] = __builtin_amdgcn_mfma_f32_16x16x32_bf16(a, wf[t][ks], acc[t], 0, 0, 0);
        }
#pragma unroll
        for (int t = 0; t < NT; ++t) {
            int n = colbase + t * 16 + lm;
#pragma unroll
            for (int j = 0; j < 4; ++j) {
                int m = rt * 16 + lk * 4 + j;
                float v = acc[t][j];
                if (n < 64) {
                    OUTY[(size_t)m * 64 + n] = (unsigned short)f2bf(v);
                } else {
                    v += bias[n - 64];
                    OUTR[(size_t)m * 64 + (n - 64)] = (unsigned short)f2bf(v);
                }
            }
        }
    }
}

// ---------------- fused layer 3: gather h2 -> LDS, dual MFMA ---------------
// h2 = relu(segsum(Y2B) + ROOT2); {y3, root3} = h2@[W3r||W3o]^T (+b3 on root).
__launch_bounds__(256, 2)
__global__ void fused_l3(const unsigned short* __restrict__ Y2B,
                         const unsigned short* __restrict__ ROOT2,
                         const int* __restrict__ rowptr, const int* __restrict__ csr,
                         const unsigned short* __restrict__ W,   // w3cat [128][64]
                         const float* __restrict__ bias,         // b3
                         unsigned short* __restrict__ OUTY,
                         unsigned short* __restrict__ OUTR) {
    __shared__ unsigned short h2[64 * 64];
    const int tid = threadIdx.x;
    const int i0 = blockIdx.x * 64;

    // Phase A: gather (32 groups x 8 lanes; 2 rows/group)
    {
        const uint4* __restrict__ X4 = (const uint4*)Y2B;
        int grp = tid >> 3, lane = tid & 7;
        for (int j = 0; j < 2; ++j) {
            int row = grp * 2 + j;
            int i = i0 + row;
            if (i >= N_NODES) break;
            int s = rowptr[i], e = rowptr[i + 1];
            float a[8] = {0.f}, b[8] = {0.f};
            int p = s;
            for (; p + 4 <= e; p += 4) {
                uint4 v0 = X4[(size_t)csr[p + 0] * 8 + lane];
                uint4 v1 = X4[(size_t)csr[p + 1] * 8 + lane];
                uint4 v2 = X4[(size_t)csr[p + 2] * 8 + lane];
                uint4 v3 = X4[(size_t)csr[p + 3] * 8 + lane];
                addv8(a, v0); addv8(b, v1); addv8(a, v2); addv8(b, v3);
            }
            if (p + 2 <= e) {
                uint4 v0 = X4[(size_t)csr[p] * 8 + lane];
                uint4 v1 = X4[(size_t)csr[p + 1] * 8 + lane];
                addv8(a, v0); addv8(b, v1);
                p += 2;
            }
            if (p < e) { uint4 v = X4[(size_t)csr[p] * 8 + lane]; addv8(a, v); }
            float f[8];
#pragma unroll
            for (int k = 0; k < 8; ++k) f[k] = a[k] + b[k];
            uint4 rr = ((const uint4*)ROOT2)[(size_t)i * 8 + lane];
            f[0] += bflo(rr.x); f[1] += bfhi(rr.x);
            f[2] += bflo(rr.y); f[3] += bfhi(rr.y);
            f[4] += bflo(rr.z); f[5] += bfhi(rr.z);
            f[6] += bflo(rr.w); f[7] += bfhi(rr.w);
#pragma unroll
            for (int k = 0; k < 8; ++k) f[k] = fmaxf(f[k], 0.f);
            *(uint4*)&h2[(row * 8 + (lane ^ (row & 7))) * 8] = packv8(f);
        }
    }
    const int l = tid & 63, wv = tid >> 6;
    const int lm = l & 15, lk = l >> 4;
    const int colbase = wv * 32;
    bf16x8 wf[2][2];
#pragma unroll
    for (int t = 0; t < 2; ++t) {
        int wrow = colbase + t * 16 + lm;
#pragma unroll
        for (int ks = 0; ks < 2; ++ks)
            wf[t][ks] = *(const bf16x8*)(W + (size_t)wrow * 64 + ks * 32 + lk * 8);
    }
    __syncthreads();
    for (int r = 0; r < 4; ++r) {
        int rt = blockIdx.x * 4 + r;
        if (rt >= N_NODES / 16) break;
        f32x4 acc0 = (f32x4){0.f, 0.f, 0.f, 0.f};
        f32x4 acc1 = (f32x4){0.f, 0.f, 0.f, 0.f};
        int ldsrow = r * 16 + lm;
#pragma unroll
        for (int ks = 0; ks < 2; ++ks) {
            int c = ks * 4 + lk;
            bf16x8 a = *(const bf16x8*)&h2[(ldsrow * 8 + (c ^ (ldsrow & 7))) * 8];
            acc0 = __builtin_amdgcn_mfma_f32_16x16x32_bf16(a, wf[0][ks], acc0, 0, 0, 0);
            acc1 = __builtin_amdgcn_mfma_f32_16x16x32_bf16(a, wf[1][ks], acc1, 0, 0, 0);
        }
#pragma unroll
        for (int t = 0; t < 2; ++t) {
            int n = colbase + t * 16 + lm;
            const f32x4& acc = t ? acc1 : acc0;
#pragma unroll
            for (int jj = 0; jj < 4; ++jj) {
                int m = rt * 16 + lk * 4 + jj;
                float v = acc[jj];
                if (n < 64) {
                    OUTY[(size_t)m * 64 + n] = (unsigned short)f2bf(v);
                } else {
                    v += bias[n - 64];
                    OUTR[(size_t)m * 64 + (n - 64)] = (unsigned short)f2bf(v);
                }
            }
        }
    }
}

// ---------------- per-graph pooling (sorted batch, bf16 input) -------------

__global__ void pool_graph(const unsigned short* __restrict__ H,
                           const int* __restrict__ batch, float* __restrict__ G) {
    int g = blockIdx.x;   // 512 blocks
    int t = threadIdx.x;  // 64 threads
    int lo = 0, hi = N_NODES;
    while (lo < hi) { int mid = (lo + hi) >> 1; if (batch[mid] < g) lo = mid + 1; else hi = mid; }
    int start = lo;
    hi = N_NODES;
    while (lo < hi) { int mid = (lo + hi) >> 1; if (batch[mid] < g + 1) lo = mid + 1; else hi = mid; }
    int end = lo;
    float acc = 0.f;
    for (int i = start; i < end; ++i)
        acc += __uint_as_float((unsigned)H[(size_t)i * 64 + t] << 16);
    G[(size_t)g * 64 + t] = acc;
}

// ---------------- MLP head + log_softmax ----------------

__global__ void mlp_head(const float* __restrict__ G, const float* __restrict__ fc1w,
                         const float* __restrict__ fc1b, const float* __restrict__ fc2w,
                         const float* __restrict__ fc2b, float* __restrict__ out) {
    int g = blockIdx.x;
    int t = threadIdx.x;  // 64
    __shared__ float gr[64], tt[64], sc[32], red[2];
    gr[t] = G[(size_t)g * 64 + t];
    __syncthreads();
    float acc = fc1b[t];
#pragma unroll
    for (int k = 0; k < 64; ++k) acc += gr[k] * fc1w[t * 64 + k];
    tt[t] = fmaxf(acc, 0.f);
    __syncthreads();
    if (t < 32) {
        float s = fc2b[t];
#pragma unroll
        for (int k = 0; k < 64; ++k) s += tt[k] * fc2w[t * 64 + k];
        sc[t] = s;
    }
    __syncthreads();
    if (t == 0) {
        float mx = sc[0];
        for (int c = 1; c < 32; ++c) mx = fmaxf(mx, sc[c]);
        float sum = 0.f;
        for (int c = 0; c < 32; ++c) sum += expf(sc[c] - mx);
        red[0] = mx; red[1] = logf(sum);
    }
    __syncthreads();
    if (t < 32) out[(size_t)g * 32 + t] = sc[t] - red[0] - red[1];
}

// ---------------- launch ----------------

extern "C" void kernel_launch(void* const* d_in, const int* in_sizes, int n_in,
                              void* d_out, int out_size, void* d_ws, size_t ws_size,
                              hipStream_t stream) {
    const float* x       = (const float*)d_in[0];
    const int*   edge    = (const int*)d_in[1];   // [2][E]: row0=src, row1=dst
    const int*   batch   = (const int*)d_in[2];
    const float* w1_rel  = (const float*)d_in[3];
    const float* b1      = (const float*)d_in[4];
    const float* w1_root = (const float*)d_in[5];
    const float* w2_rel  = (const float*)d_in[6];
    const float* b2      = (const float*)d_in[7];
    const float* w2_root = (const float*)d_in[8];
    const float* w3_rel  = (const float*)d_in[9];
    const float* b3      = (const float*)d_in[10];
    const float* w3_root = (const float*)d_in[11];
    const float* fc1w    = (const float*)d_in[12];
    const float* fc1b    = (const float*)d_in[13];
    const float* fc2w    = (const float*)d_in[14];
    const float* fc2b    = (const float*)d_in[15];
    float* out = (float*)d_out;

    char* p = (char*)d_ws;
    size_t used = 0;
    auto alloc = [&](size_t bytes) {
        char* r = p + used;
        used += (bytes + 255) & ~(size_t)255;
        return r;
    };
    int*            rowptr = (int*)alloc((N_NODES + 1) * sizeof(int));
    int*            cursor = (int*)alloc(N_NODES * sizeof(int));
    int*            csr    = (int*)alloc(N_EDGES * sizeof(int));
    int*            bsum   = (int*)alloc(SCAN_NB * sizeof(int));
    unsigned short* wbf    = (unsigned short*)alloc(57344 * sizeof(unsigned short));
    unsigned short* bufX   = (unsigned short*)alloc((size_t)N_NODES * 128 * 2);  // region X
    unsigned short* bufA   = (unsigned short*)alloc((size_t)N_NODES * 128 * 2);  // region A
    unsigned short* bufH   = (unsigned short*)alloc((size_t)N_NODES * 128 * 2);  // region H
    float*          G      = (float*)alloc((size_t)N_GRAPHS * 64 * sizeof(float));

    if (used > ws_size) return;  // clean bail instead of wild writes

    // bf16 weight views
    unsigned short* w1r_bf = wbf;          // [128][128]
    unsigned short* w1o_bf = wbf + 16384;  // [128][128]
    unsigned short* w2cat  = wbf + 32768;  // [128][128]: w2_rel || w2_root
    unsigned short* w3cat  = wbf + 49152;  // [128][64] : w3_rel || w3_root

    // Region aliasing timeline (tenant dead before reuse):
    unsigned short* XB    = bufX;                          // [N,128] bf16 (dead after fused_l1)
    unsigned short* H1b   = bufH;                          // [N,128] bf16 (dead after gemm_dual)
    unsigned short* Y2B   = bufA;                          // [N,64] bf16
    unsigned short* ROOT2 = bufA + (size_t)N_NODES * 64;   // [N,64] bf16
    unsigned short* Y3B   = bufX;                          // [N,64] bf16 (XB dead)
    unsigned short* ROOT3 = bufX + (size_t)N_NODES * 64;   // [N,64] bf16
    unsigned short* H3b   = bufH;                          // [N,64] bf16 (H1b dead)

    // 1. fused init
    init_kernel<<<F2BF_BLOCKS + ZR_BLOCKS + WC_BLOCKS + ZG_BLOCKS, 256, 0, stream>>>(
        x, (uint2*)XB, rowptr, w1_rel, w1_root, w2_rel, w2_root, w3_rel, w3_root, wbf, G);

    // 2-5. CSR build
    hist_kernel<<<(N_EDGES + 255) / 256, 256, 0, stream>>>(edge, rowptr);
    scan_reduce_kernel<<<SCAN_NB, 256, 0, stream>>>(rowptr, bsum);
    scan_apply_kernel<<<SCAN_NB, 256, 0, stream>>>(rowptr, bsum, cursor);
    scatter_kernel<<<(N_EDGES + 255) / 256, 256, 0, stream>>>(edge, cursor, csr);

    int gblk = (N_NODES + 63) / 64;  // 782 blocks (4 row-tiles each)

    // 6. Layer 1 fused: gather aggr1 -> LDS, h1 = relu(aggr1@W1r + x@W1o + b1)
    fused_l1<<<gblk, 256, 0, stream>>>(XB, rowptr, csr, w1r_bf, w1o_bf, b1, H1b);

    // 7. Layer 2 GEMM: {y2, root2} = h1@[W2r||W2o] (+b2 on root)
    gemm_dual<4><<<gblk, 256, 0, stream>>>(H1b, w2cat, b2, Y2B, ROOT2);

    // 8. Layer 3 fused: h2 = relu(segsum(y2)+root2) -> LDS; {y3, root3} = h2@[W3r||W3o]
    fused_l3<<<gblk, 256, 0, stream>>>(Y2B, ROOT2, rowptr, csr, w3cat, b3, Y3B, ROOT3);

    // 9. Layer 3 aggregate: h3 = segsum(y3) + root3 (bf16)
    aggregate_root<8><<<(N_NODES + 31) / 32, 256, 0, stream>>>(Y3B, rowptr, csr, ROOT3, H3b);

    // 10-11. Pool + head
    pool_graph<<<N_GRAPHS, 64, 0, stream>>>(H3b, batch, G);
    mlp_head<<<N_GRAPHS, 64, 0, stream>>>(G, fc1w, fc1b, fc2w, fc2b, out);
}